// Round 1
// baseline (11549.612 us; speedup 1.0000x reference)
//
#include <hip/hip_runtime.h>

// ---------------------------------------------------------------------------
// GCN forward: 3x GCNConv(+relu) -> global_mean_pool -> fc -> log_softmax
// Sizes: N=100000 nodes, E=3200000 edges, G=512 graphs, feats 128->64->128->64
// ---------------------------------------------------------------------------

static inline int grid_for(long long total, int block) {
    return (int)((total + block - 1) / block);
}

// --- degree / dinv ---------------------------------------------------------
__global__ void k_deg_init(float* deg, int n) {
    int i = blockIdx.x * blockDim.x + threadIdx.x;
    if (i < n) deg[i] = 1.0f;  // self-loop contributes 1
}

__global__ void k_deg_accum(const int* __restrict__ dst, float* deg, int E) {
    int i = blockIdx.x * blockDim.x + threadIdx.x;
    if (i < E) atomicAdd(&deg[dst[i]], 1.0f);
}

__global__ void k_rsqrt_inplace(float* d, int n) {
    int i = blockIdx.x * blockDim.x + threadIdx.x;
    if (i < n) d[i] = rsqrtf(d[i]);  // deg >= 1 always (self-loops)
}

__global__ void k_edge_norm(const int* __restrict__ src, const int* __restrict__ dst,
                            const float* __restrict__ dinv, float* __restrict__ nrm, int E) {
    int i = blockIdx.x * blockDim.x + threadIdx.x;
    if (i < E) nrm[i] = dinv[src[i]] * dinv[dst[i]];
}

// --- dense GEMM: H[N,OUT] = X[N,IN] @ W[IN,OUT] ----------------------------
template <int IN, int OUT>
__global__ void k_gemm(const float* __restrict__ X, const float* __restrict__ W,
                       float* __restrict__ H, int N) {
    __shared__ float w[IN * OUT];  // 8192 floats = 32 KB for both shapes
    for (int i = threadIdx.x; i < IN * OUT; i += blockDim.x) w[i] = W[i];
    __syncthreads();
    constexpr int RPB = 256 / OUT;
    int col = threadIdx.x % OUT;
    int rl  = threadIdx.x / OUT;
    int row = blockIdx.x * RPB + rl;
    if (row >= N) return;
    const float* xr = X + (size_t)row * IN;
    float acc = 0.0f;
#pragma unroll
    for (int k = 0; k < IN; ++k) acc = fmaf(xr[k], w[k * OUT + col], acc);
    H[(size_t)row * OUT + col] = acc;
}

// --- self-loop init: O[i,f] = H[i,f] * dinv[i]^2 ---------------------------
template <int F>
__global__ void k_selfloop(const float* __restrict__ H, const float* __restrict__ dinv,
                           float* __restrict__ O, int N) {
    long long idx = (long long)blockIdx.x * blockDim.x + threadIdx.x;
    if (idx >= (long long)N * F) return;
    int i = (int)(idx >> (F == 128 ? 7 : 6));
    float dv = dinv[i];
    O[idx] = H[idx] * dv * dv;
}

// --- edge scatter-add: O[dst] += H[src] * nrm ------------------------------
template <int F>
__global__ void k_agg(const int* __restrict__ src, const int* __restrict__ dst,
                      const float* __restrict__ nrm, const float* __restrict__ H,
                      float* __restrict__ O, int E) {
    constexpr int CH = F / 4;  // float4 chunks per edge
    long long idx = (long long)blockIdx.x * blockDim.x + threadIdx.x;
    long long total = (long long)E * CH;
    if (idx >= total) return;
    int e  = (int)(idx / CH);
    int fq = (int)(idx % CH);
    int s = src[e], d = dst[e];
    float w = nrm[e];
    const float4 hv = *reinterpret_cast<const float4*>(H + (size_t)s * F + fq * 4);
    float* op = O + (size_t)d * F + fq * 4;
    atomicAdd(op + 0, hv.x * w);
    atomicAdd(op + 1, hv.y * w);
    atomicAdd(op + 2, hv.z * w);
    atomicAdd(op + 3, hv.w * w);
}

// --- bias + relu -----------------------------------------------------------
template <int F>
__global__ void k_bias_relu(float* __restrict__ O, const float* __restrict__ b, int N) {
    long long idx = (long long)blockIdx.x * blockDim.x + threadIdx.x;
    if (idx >= (long long)N * F) return;
    int f = (int)(idx & (F - 1));
    O[idx] = fmaxf(O[idx] + b[f], 0.0f);
}

// --- pooling ---------------------------------------------------------------
__global__ void k_zero(float* p, int n) {
    int i = blockIdx.x * blockDim.x + threadIdx.x;
    if (i < n) p[i] = 0.0f;
}

__global__ void k_pool(const float* __restrict__ H, const int* __restrict__ batch,
                       float* __restrict__ sums, float* __restrict__ cnt, int N) {
    long long idx = (long long)blockIdx.x * blockDim.x + threadIdx.x;
    if (idx >= (long long)N * 64) return;
    int i = (int)(idx >> 6);
    int f = (int)(idx & 63);
    int g = batch[i];
    atomicAdd(&sums[(size_t)g * 64 + f], H[idx]);
    if (f == 0) atomicAdd(&cnt[g], 1.0f);
}

// --- head: mean, fc, log_softmax ------------------------------------------
__global__ void k_head(const float* __restrict__ sums, const float* __restrict__ cnt,
                       const float* __restrict__ fcw, const float* __restrict__ fcb,
                       float* __restrict__ out, int G) {
    int g = blockIdx.x * blockDim.x + threadIdx.x;
    if (g >= G) return;
    float inv = 1.0f / fmaxf(cnt[g], 1.0f);
    float l[6];
#pragma unroll
    for (int c = 0; c < 6; ++c) {
        float acc = fcb[c];
        for (int f = 0; f < 64; ++f)
            acc = fmaf(sums[(size_t)g * 64 + f] * inv, fcw[f * 6 + c], acc);
        l[c] = acc;
    }
    float m = l[0];
#pragma unroll
    for (int c = 1; c < 6; ++c) m = fmaxf(m, l[c]);
    float se = 0.0f;
#pragma unroll
    for (int c = 0; c < 6; ++c) se += expf(l[c] - m);
    float lse = m + logf(se);
#pragma unroll
    for (int c = 0; c < 6; ++c) out[(size_t)g * 6 + c] = l[c] - lse;
}

// ---------------------------------------------------------------------------
extern "C" void kernel_launch(void* const* d_in, const int* in_sizes, int n_in,
                              void* d_out, int out_size, void* d_ws, size_t ws_size,
                              hipStream_t stream) {
    const float* x    = (const float*)d_in[0];
    const int*   eidx = (const int*)d_in[1];
    const int*   batch= (const int*)d_in[2];
    const float* W1   = (const float*)d_in[3];
    const float* b1   = (const float*)d_in[4];
    const float* W2   = (const float*)d_in[5];
    const float* b2   = (const float*)d_in[6];
    const float* W3   = (const float*)d_in[7];
    const float* b3   = (const float*)d_in[8];
    const float* fcw  = (const float*)d_in[9];
    const float* fcb  = (const float*)d_in[10];
    float* out = (float*)d_out;

    const int N = in_sizes[2];          // 100000
    const int E = in_sizes[1] / 2;      // 3200000
    const int G = out_size / 6;         // 512

    const int* src = eidx;
    const int* dst = eidx + E;

    // workspace layout (floats), 64B-aligned chunks
    float* ws = (float*)d_ws;
    size_t off = 0;
    auto take = [&](size_t nfloats) {
        float* p = ws + off;
        off += (nfloats + 15) & ~(size_t)15;
        return p;
    };
    float* dinv = take((size_t)N);
    float* nrm  = take((size_t)E);
    float* bufA = take((size_t)N * 128);  // GEMM output h
    float* bufB = take((size_t)N * 128);  // aggregated output / next layer input
    float* sums = take((size_t)G * 64);
    float* cnt  = take((size_t)G);
    (void)ws_size;

    const int B = 256;

    // degrees -> dinv -> per-edge norm
    k_deg_init<<<grid_for(N, B), B, 0, stream>>>(dinv, N);
    k_deg_accum<<<grid_for(E, B), B, 0, stream>>>(dst, dinv, E);
    k_rsqrt_inplace<<<grid_for(N, B), B, 0, stream>>>(dinv, N);
    k_edge_norm<<<grid_for(E, B), B, 0, stream>>>(src, dst, dinv, nrm, E);

    // ---- layer 1: x[N,128] -> h[N,64] -> agg -> relu (bufB[N,64]) ----
    k_gemm<128, 64><<<grid_for(N, 4) , B, 0, stream>>>(x, W1, bufA, N);
    k_selfloop<64><<<grid_for((long long)N * 64, B), B, 0, stream>>>(bufA, dinv, bufB, N);
    k_agg<64><<<grid_for((long long)E * 16, B), B, 0, stream>>>(src, dst, nrm, bufA, bufB, E);
    k_bias_relu<64><<<grid_for((long long)N * 64, B), B, 0, stream>>>(bufB, b1, N);

    // ---- layer 2: bufB[N,64] -> h[N,128] -> agg -> relu (bufB[N,128]) ----
    k_gemm<64, 128><<<grid_for(N, 2), B, 0, stream>>>(bufB, W2, bufA, N);
    k_selfloop<128><<<grid_for((long long)N * 128, B), B, 0, stream>>>(bufA, dinv, bufB, N);
    k_agg<128><<<grid_for((long long)E * 32, B), B, 0, stream>>>(src, dst, nrm, bufA, bufB, E);
    k_bias_relu<128><<<grid_for((long long)N * 128, B), B, 0, stream>>>(bufB, b2, N);

    // ---- layer 3: bufB[N,128] -> h[N,64] -> agg -> relu (bufB[N,64]) ----
    k_gemm<128, 64><<<grid_for(N, 4), B, 0, stream>>>(bufB, W3, bufA, N);
    k_selfloop<64><<<grid_for((long long)N * 64, B), B, 0, stream>>>(bufA, dinv, bufB, N);
    k_agg<64><<<grid_for((long long)E * 16, B), B, 0, stream>>>(src, dst, nrm, bufA, bufB, E);
    k_bias_relu<64><<<grid_for((long long)N * 64, B), B, 0, stream>>>(bufB, b3, N);

    // ---- pool + head ----
    k_zero<<<grid_for(G * 64 + G, B), B, 0, stream>>>(sums, G * 64 + G);  // sums then cnt contiguous
    // note: cnt must directly follow sums for the single zero pass
    // (layout above pads to 16-float boundary; zero both explicitly instead)
    k_zero<<<grid_for(G, B), B, 0, stream>>>(cnt, G);
    k_pool<<<grid_for((long long)N * 64, B), B, 0, stream>>>(bufB, batch, sums, cnt, N);
    k_head<<<grid_for(G, 64), 64, 0, stream>>>(sums, cnt, fcw, fcb, out, G);
}

// Round 2
// 1682.292 us; speedup vs baseline: 6.8654x; 6.8654x over previous
//
#include <hip/hip_runtime.h>

// ---------------------------------------------------------------------------
// GCN forward: 3x GCNConv(+relu) -> global_mean_pool -> fc -> log_softmax
// N=100000 nodes, E=3200000 edges, G=512 graphs, feats 128->64->128->64
// Strategy: build dst-sorted CSR per call (counting sort), then aggregation is
// gather-style (wave per node, lane per feature, register accum, one store) —
// zero atomics in the hot path.
// ---------------------------------------------------------------------------

static inline int grid_for(long long total, int block) {
    return (int)((total + block - 1) / block);
}

// --- CSR build -------------------------------------------------------------
__global__ void k_zero_int(int* p, int n) {
    int i = blockIdx.x * blockDim.x + threadIdx.x;
    if (i < n) p[i] = 0;
}

__global__ void k_count(const int* __restrict__ dst, int* __restrict__ counts, int E) {
    int i = blockIdx.x * blockDim.x + threadIdx.x;
    if (i < E) atomicAdd(&counts[dst[i]], 1);
}

// per-block inclusive scan of counts -> rowoff (inclusive), block sums -> partials
__global__ void k_scan_block(const int* __restrict__ counts, int* __restrict__ rowoff,
                             int* __restrict__ partials, int N) {
    __shared__ int s[256];
    int tid = threadIdx.x;
    int i = blockIdx.x * 256 + tid;
    int v = (i < N) ? counts[i] : 0;
    s[tid] = v;
    __syncthreads();
    for (int off = 1; off < 256; off <<= 1) {
        int t = (tid >= off) ? s[tid - off] : 0;
        __syncthreads();
        s[tid] += t;
        __syncthreads();
    }
    if (i < N) rowoff[i] = s[tid];
    if (tid == 255) partials[blockIdx.x] = s[255];
}

// single-block exclusive scan of partials (NBLK <= 512)
__global__ void k_scan_partials(int* __restrict__ partials, int nblk) {
    __shared__ int s[512];
    int tid = threadIdx.x;
    int v = (tid < nblk) ? partials[tid] : 0;
    s[tid] = v;
    __syncthreads();
    for (int off = 1; off < 512; off <<= 1) {
        int t = (tid >= off) ? s[tid - off] : 0;
        __syncthreads();
        s[tid] += t;
        __syncthreads();
    }
    if (tid < nblk) partials[tid] = s[tid] - v;  // exclusive
}

// rowoff := exclusive scan; cursor := rowoff; dinv := rsqrt(deg+1)
__global__ void k_finalize(const int* __restrict__ counts, int* __restrict__ rowoff,
                           const int* __restrict__ partials, int* __restrict__ cursor,
                           float* __restrict__ dinv, int N) {
    int i = blockIdx.x * blockDim.x + threadIdx.x;
    if (i >= N) return;
    int excl = rowoff[i] - counts[i] + partials[i >> 8];
    rowoff[i] = excl;
    cursor[i] = excl;
    dinv[i] = rsqrtf((float)counts[i] + 1.0f);
}

__global__ void k_scatter(const int* __restrict__ src, const int* __restrict__ dst,
                          int* __restrict__ cursor, int* __restrict__ srt, int E) {
    int i = blockIdx.x * blockDim.x + threadIdx.x;
    if (i >= E) return;
    int d = dst[i];
    int pos = atomicAdd(&cursor[d], 1);
    srt[pos] = src[i];
}

// --- dense GEMM: H[N,OUT] = X[N,IN] @ W[IN,OUT] ----------------------------
template <int IN, int OUT>
__global__ void k_gemm(const float* __restrict__ X, const float* __restrict__ W,
                       float* __restrict__ H, int N) {
    __shared__ float w[IN * OUT];  // 32 KB for both shapes
    for (int i = threadIdx.x; i < IN * OUT; i += blockDim.x) w[i] = W[i];
    __syncthreads();
    constexpr int RPB = 256 / OUT;
    int col = threadIdx.x % OUT;
    int rl  = threadIdx.x / OUT;
    int row = blockIdx.x * RPB + rl;
    if (row >= N) return;
    const float* xr = X + (size_t)row * IN;
    float acc = 0.0f;
#pragma unroll
    for (int k = 0; k < IN; ++k) acc = fmaf(xr[k], w[k * OUT + col], acc);
    H[(size_t)row * OUT + col] = acc;
}

// --- fused aggregation: O[d] = relu(bias + sum_{e: dst=d} H[src]*w + H[d]*dinv[d]^2)
// one wave per node, lane = feature (F=64)
__global__ void k_agg_csr64(const int* __restrict__ srt, const int* __restrict__ rowoff,
                            const int* __restrict__ counts, const float* __restrict__ dinv,
                            const float* __restrict__ H, const float* __restrict__ bias,
                            float* __restrict__ O, int N) {
    int node = blockIdx.x * (blockDim.x >> 6) + (threadIdx.x >> 6);
    int lane = threadIdx.x & 63;
    if (node >= N) return;
    float dv = dinv[node];
    float acc = H[(size_t)node * 64 + lane] * dv * dv;  // self-loop
    const int* sp = srt + rowoff[node];
    int ce = counts[node];
    int e = 0;
    for (; e + 1 < ce; e += 2) {
        int sa = sp[e], sb = sp[e + 1];
        float wa = dinv[sa] * dv;
        float wb = dinv[sb] * dv;
        float ha = H[(size_t)sa * 64 + lane];
        float hb = H[(size_t)sb * 64 + lane];
        acc = fmaf(ha, wa, acc);
        acc = fmaf(hb, wb, acc);
    }
    if (e < ce) {
        int sa = sp[e];
        acc = fmaf(H[(size_t)sa * 64 + lane], dinv[sa] * dv, acc);
    }
    O[(size_t)node * 64 + lane] = fmaxf(acc + bias[lane], 0.0f);
}

// F=128: lane handles one float2
__global__ void k_agg_csr128(const int* __restrict__ srt, const int* __restrict__ rowoff,
                             const int* __restrict__ counts, const float* __restrict__ dinv,
                             const float* __restrict__ H, const float* __restrict__ bias,
                             float* __restrict__ O, int N) {
    int node = blockIdx.x * (blockDim.x >> 6) + (threadIdx.x >> 6);
    int lane = threadIdx.x & 63;
    if (node >= N) return;
    const float2* H2 = (const float2*)H;
    float dv = dinv[node];
    float2 hv = H2[(size_t)node * 64 + lane];
    float ax = hv.x * dv * dv, ay = hv.y * dv * dv;  // self-loop
    const int* sp = srt + rowoff[node];
    int ce = counts[node];
    int e = 0;
    for (; e + 1 < ce; e += 2) {
        int sa = sp[e], sb = sp[e + 1];
        float wa = dinv[sa] * dv;
        float wb = dinv[sb] * dv;
        float2 va = H2[(size_t)sa * 64 + lane];
        float2 vb = H2[(size_t)sb * 64 + lane];
        ax = fmaf(va.x, wa, ax); ay = fmaf(va.y, wa, ay);
        ax = fmaf(vb.x, wb, ax); ay = fmaf(vb.y, wb, ay);
    }
    if (e < ce) {
        int sa = sp[e];
        float wa = dinv[sa] * dv;
        float2 va = H2[(size_t)sa * 64 + lane];
        ax = fmaf(va.x, wa, ax); ay = fmaf(va.y, wa, ay);
    }
    float2 b2 = ((const float2*)bias)[lane];
    float2 o;
    o.x = fmaxf(ax + b2.x, 0.0f);
    o.y = fmaxf(ay + b2.y, 0.0f);
    ((float2*)O)[(size_t)node * 64 + lane] = o;
}

// --- pooling (batch is sorted): wave-run accumulation, flush at graph change
__global__ void k_zero_f(float* p, int n) {
    int i = blockIdx.x * blockDim.x + threadIdx.x;
    if (i < n) p[i] = 0.0f;
}

__global__ void k_pool_seg(const float* __restrict__ H, const int* __restrict__ batch,
                           float* __restrict__ sums, float* __restrict__ cnt, int N) {
    int gw = (blockIdx.x * blockDim.x + threadIdx.x) >> 6;
    int lane = threadIdx.x & 63;
    int start = gw * 64;
    if (start >= N) return;
    int end = min(N, start + 64);
    int gcur = batch[start];
    float acc = 0.0f, c = 0.0f;
    for (int i = start; i < end; ++i) {
        int g = batch[i];
        if (g != gcur) {
            atomicAdd(&sums[(size_t)gcur * 64 + lane], acc);
            if (lane == 0) atomicAdd(&cnt[gcur], c);
            acc = 0.0f; c = 0.0f; gcur = g;
        }
        acc += H[(size_t)i * 64 + lane];
        c += 1.0f;
    }
    atomicAdd(&sums[(size_t)gcur * 64 + lane], acc);
    if (lane == 0) atomicAdd(&cnt[gcur], c);
}

// --- head: mean, fc, log_softmax ------------------------------------------
__global__ void k_head(const float* __restrict__ sums, const float* __restrict__ cnt,
                       const float* __restrict__ fcw, const float* __restrict__ fcb,
                       float* __restrict__ out, int G) {
    int g = blockIdx.x * blockDim.x + threadIdx.x;
    if (g >= G) return;
    float inv = 1.0f / fmaxf(cnt[g], 1.0f);
    float l[6];
#pragma unroll
    for (int c = 0; c < 6; ++c) {
        float acc = fcb[c];
        for (int f = 0; f < 64; ++f)
            acc = fmaf(sums[(size_t)g * 64 + f] * inv, fcw[f * 6 + c], acc);
        l[c] = acc;
    }
    float m = l[0];
#pragma unroll
    for (int c = 1; c < 6; ++c) m = fmaxf(m, l[c]);
    float se = 0.0f;
#pragma unroll
    for (int c = 0; c < 6; ++c) se += expf(l[c] - m);
    float lse = m + logf(se);
#pragma unroll
    for (int c = 0; c < 6; ++c) out[(size_t)g * 6 + c] = l[c] - lse;
}

// ---------------------------------------------------------------------------
extern "C" void kernel_launch(void* const* d_in, const int* in_sizes, int n_in,
                              void* d_out, int out_size, void* d_ws, size_t ws_size,
                              hipStream_t stream) {
    const float* x    = (const float*)d_in[0];
    const int*   eidx = (const int*)d_in[1];
    const int*   batch= (const int*)d_in[2];
    const float* W1   = (const float*)d_in[3];
    const float* b1   = (const float*)d_in[4];
    const float* W2   = (const float*)d_in[5];
    const float* b2   = (const float*)d_in[6];
    const float* W3   = (const float*)d_in[7];
    const float* b3   = (const float*)d_in[8];
    const float* fcw  = (const float*)d_in[9];
    const float* fcb  = (const float*)d_in[10];
    float* out = (float*)d_out;

    const int N = in_sizes[2];          // 100000
    const int E = in_sizes[1] / 2;      // 3200000
    const int G = out_size / 6;         // 512

    const int* src = eidx;
    const int* dst = eidx + E;

    // workspace layout (4B units)
    float* ws = (float*)d_ws;
    size_t off = 0;
    auto take = [&](size_t n4) {
        float* p = ws + off;
        off += (n4 + 15) & ~(size_t)15;
        return p;
    };
    float* dinv    = take((size_t)N);
    int*   srt     = (int*)take((size_t)E);
    int*   rowoff  = (int*)take((size_t)N);
    int*   counts  = (int*)take((size_t)N);
    int*   cursor  = (int*)take((size_t)N);
    int*   partials= (int*)take(512);
    float* bufA    = take((size_t)N * 128);
    float* bufB    = take((size_t)N * 128);
    float* sums    = take((size_t)G * 64);
    float* cnt     = take((size_t)G);
    (void)ws_size;

    const int B = 256;
    const int NBLK = grid_for(N, 256);  // 391 for N=100000

    // --- CSR build ---
    k_zero_int<<<grid_for(N, B), B, 0, stream>>>(counts, N);
    k_count<<<grid_for(E, B), B, 0, stream>>>(dst, counts, E);
    k_scan_block<<<NBLK, 256, 0, stream>>>(counts, rowoff, partials, N);
    k_scan_partials<<<1, 512, 0, stream>>>(partials, NBLK);
    k_finalize<<<grid_for(N, B), B, 0, stream>>>(counts, rowoff, partials, cursor, dinv, N);
    k_scatter<<<grid_for(E, B), B, 0, stream>>>(src, dst, cursor, srt, E);

    // --- layer 1: x[N,128] -> h[N,64] -> agg+relu -> bufB[N,64] ---
    k_gemm<128, 64><<<grid_for(N, 4), B, 0, stream>>>(x, W1, bufA, N);
    k_agg_csr64<<<grid_for(N, 4), B, 0, stream>>>(srt, rowoff, counts, dinv, bufA, b1, bufB, N);

    // --- layer 2: bufB[N,64] -> h[N,128] -> agg+relu -> bufB[N,128] ---
    k_gemm<64, 128><<<grid_for(N, 2), B, 0, stream>>>(bufB, W2, bufA, N);
    k_agg_csr128<<<grid_for(N, 4), B, 0, stream>>>(srt, rowoff, counts, dinv, bufA, b2, bufB, N);

    // --- layer 3: bufB[N,128] -> h[N,64] -> agg+relu -> bufB[N,64] ---
    k_gemm<128, 64><<<grid_for(N, 4), B, 0, stream>>>(bufB, W3, bufA, N);
    k_agg_csr64<<<grid_for(N, 4), B, 0, stream>>>(srt, rowoff, counts, dinv, bufA, b3, bufB, N);

    // --- pool + head ---
    k_zero_f<<<grid_for(G * 64, B), B, 0, stream>>>(sums, G * 64);
    k_zero_f<<<grid_for(G, B), B, 0, stream>>>(cnt, G);
    k_pool_seg<<<grid_for((long long)grid_for(N, 64) * 64, B), B, 0, stream>>>(bufB, batch, sums, cnt, N);
    k_head<<<grid_for(G, 64), 64, 0, stream>>>(sums, cnt, fcw, fcb, out, G);
}

// Round 3
// 1136.551 us; speedup vs baseline: 10.1620x; 1.4802x over previous
//
#include <hip/hip_runtime.h>

// ---------------------------------------------------------------------------
// GCN forward: 3x GCNConv(+relu) -> global_mean_pool -> fc -> log_softmax
// N=100000 nodes, E=3200000 edges, G=512 graphs, feats 128->64->128->64
// R2: register-blocked tiled fp32 GEMM (64-row tiles, 4xTN per thread).
// Aggregation stays CSR gather-style (no atomics in hot path).
// ---------------------------------------------------------------------------

static inline int grid_for(long long total, int block) {
    return (int)((total + block - 1) / block);
}

// --- CSR build -------------------------------------------------------------
__global__ void k_zero_int(int* p, int n) {
    int i = blockIdx.x * blockDim.x + threadIdx.x;
    if (i < n) p[i] = 0;
}

__global__ void k_count(const int* __restrict__ dst, int* __restrict__ counts, int E) {
    int i = blockIdx.x * blockDim.x + threadIdx.x;
    if (i < E) atomicAdd(&counts[dst[i]], 1);
}

__global__ void k_scan_block(const int* __restrict__ counts, int* __restrict__ rowoff,
                             int* __restrict__ partials, int N) {
    __shared__ int s[256];
    int tid = threadIdx.x;
    int i = blockIdx.x * 256 + tid;
    int v = (i < N) ? counts[i] : 0;
    s[tid] = v;
    __syncthreads();
    for (int off = 1; off < 256; off <<= 1) {
        int t = (tid >= off) ? s[tid - off] : 0;
        __syncthreads();
        s[tid] += t;
        __syncthreads();
    }
    if (i < N) rowoff[i] = s[tid];
    if (tid == 255) partials[blockIdx.x] = s[255];
}

__global__ void k_scan_partials(int* __restrict__ partials, int nblk) {
    __shared__ int s[512];
    int tid = threadIdx.x;
    int v = (tid < nblk) ? partials[tid] : 0;
    s[tid] = v;
    __syncthreads();
    for (int off = 1; off < 512; off <<= 1) {
        int t = (tid >= off) ? s[tid - off] : 0;
        __syncthreads();
        s[tid] += t;
        __syncthreads();
    }
    if (tid < nblk) partials[tid] = s[tid] - v;  // exclusive
}

__global__ void k_finalize(const int* __restrict__ counts, int* __restrict__ rowoff,
                           const int* __restrict__ partials, int* __restrict__ cursor,
                           float* __restrict__ dinv, int N) {
    int i = blockIdx.x * blockDim.x + threadIdx.x;
    if (i >= N) return;
    int excl = rowoff[i] - counts[i] + partials[i >> 8];
    rowoff[i] = excl;
    cursor[i] = excl;
    dinv[i] = rsqrtf((float)counts[i] + 1.0f);
}

__global__ void k_scatter(const int* __restrict__ src, const int* __restrict__ dst,
                          int* __restrict__ cursor, int* __restrict__ srt, int E) {
    int i = blockIdx.x * blockDim.x + threadIdx.x;
    if (i >= E) return;
    int d = dst[i];
    int pos = atomicAdd(&cursor[d], 1);
    srt[pos] = src[i];
}

// --- register-blocked tiled GEMM: H[N,OUT] = X[N,IN] @ W[IN,OUT] -----------
// 64-row tile, 256 threads = 16x16 thread grid, each thread 4 rows x TN cols.
template <int IN, int OUT, int TN>
__global__ __launch_bounds__(256) void k_gemm_tile(const float* __restrict__ X,
                                                   const float* __restrict__ W,
                                                   float* __restrict__ H, int N) {
    constexpr int ROWS = 64;
    constexpr int CT = OUT / TN;    // 16 for both shapes
    constexpr int RT = 256 / CT;    // 16
    constexpr int TM = ROWS / RT;   // 4
    static_assert(CT * RT == 256 && TM * RT == ROWS, "tile mismatch");
    __shared__ float Xs[ROWS][IN];  // 32 KB (IN=128) / 16 KB (IN=64)
    __shared__ float Ws[IN][OUT];   // 32 KB both

    const int tid = threadIdx.x;
    const int row0 = blockIdx.x * ROWS;

    // stage W (coalesced float4)
    for (int i = tid; i < IN * OUT / 4; i += 256)
        ((float4*)Ws)[i] = ((const float4*)W)[i];
    // stage X tile (row-major, coalesced float4; zero-fill past N)
    for (int i = tid; i < ROWS * IN / 4; i += 256) {
        int r = i / (IN / 4), kq = i % (IN / 4);
        float4 v = make_float4(0.f, 0.f, 0.f, 0.f);
        if (row0 + r < N) v = *(const float4*)(X + (size_t)(row0 + r) * IN + kq * 4);
        *(float4*)&Xs[r][kq * 4] = v;
    }
    __syncthreads();

    const int tx = tid % CT;
    const int ty = tid / CT;

    float acc[TM][TN];
#pragma unroll
    for (int m = 0; m < TM; ++m)
#pragma unroll
        for (int n = 0; n < TN; ++n) acc[m][n] = 0.0f;

#pragma unroll 2
    for (int kq = 0; kq < IN / 4; ++kq) {
        float a[TM][4];
#pragma unroll
        for (int m = 0; m < TM; ++m) {
            float4 t = *(const float4*)&Xs[ty * TM + m][kq * 4];
            a[m][0] = t.x; a[m][1] = t.y; a[m][2] = t.z; a[m][3] = t.w;
        }
#pragma unroll
        for (int j = 0; j < 4; ++j) {
            float b[TN];
#pragma unroll
            for (int n4 = 0; n4 < TN / 4; ++n4) {
                float4 t = *(const float4*)&Ws[kq * 4 + j][tx * TN + n4 * 4];
                b[n4 * 4 + 0] = t.x; b[n4 * 4 + 1] = t.y;
                b[n4 * 4 + 2] = t.z; b[n4 * 4 + 3] = t.w;
            }
#pragma unroll
            for (int m = 0; m < TM; ++m)
#pragma unroll
                for (int n = 0; n < TN; ++n)
                    acc[m][n] = fmaf(a[m][j], b[n], acc[m][n]);
        }
    }

#pragma unroll
    for (int m = 0; m < TM; ++m) {
        int r = row0 + ty * TM + m;
        if (r >= N) continue;
#pragma unroll
        for (int n4 = 0; n4 < TN / 4; ++n4) {
            float4 o = make_float4(acc[m][n4 * 4 + 0], acc[m][n4 * 4 + 1],
                                   acc[m][n4 * 4 + 2], acc[m][n4 * 4 + 3]);
            *(float4*)(H + (size_t)r * OUT + tx * TN + n4 * 4) = o;
        }
    }
}

// --- fused aggregation: O[d] = relu(bias + sum_{e: dst=d} H[src]*w + H[d]*dinv^2)
__global__ void k_agg_csr64(const int* __restrict__ srt, const int* __restrict__ rowoff,
                            const int* __restrict__ counts, const float* __restrict__ dinv,
                            const float* __restrict__ H, const float* __restrict__ bias,
                            float* __restrict__ O, int N) {
    int node = blockIdx.x * (blockDim.x >> 6) + (threadIdx.x >> 6);
    int lane = threadIdx.x & 63;
    if (node >= N) return;
    float dv = dinv[node];
    float acc = H[(size_t)node * 64 + lane] * dv * dv;  // self-loop
    const int* sp = srt + rowoff[node];
    int ce = counts[node];
    int e = 0;
    for (; e + 1 < ce; e += 2) {
        int sa = sp[e], sb = sp[e + 1];
        float wa = dinv[sa] * dv;
        float wb = dinv[sb] * dv;
        float ha = H[(size_t)sa * 64 + lane];
        float hb = H[(size_t)sb * 64 + lane];
        acc = fmaf(ha, wa, acc);
        acc = fmaf(hb, wb, acc);
    }
    if (e < ce) {
        int sa = sp[e];
        acc = fmaf(H[(size_t)sa * 64 + lane], dinv[sa] * dv, acc);
    }
    O[(size_t)node * 64 + lane] = fmaxf(acc + bias[lane], 0.0f);
}

__global__ void k_agg_csr128(const int* __restrict__ srt, const int* __restrict__ rowoff,
                             const int* __restrict__ counts, const float* __restrict__ dinv,
                             const float* __restrict__ H, const float* __restrict__ bias,
                             float* __restrict__ O, int N) {
    int node = blockIdx.x * (blockDim.x >> 6) + (threadIdx.x >> 6);
    int lane = threadIdx.x & 63;
    if (node >= N) return;
    const float2* H2 = (const float2*)H;
    float dv = dinv[node];
    float2 hv = H2[(size_t)node * 64 + lane];
    float ax = hv.x * dv * dv, ay = hv.y * dv * dv;  // self-loop
    const int* sp = srt + rowoff[node];
    int ce = counts[node];
    int e = 0;
    for (; e + 1 < ce; e += 2) {
        int sa = sp[e], sb = sp[e + 1];
        float wa = dinv[sa] * dv;
        float wb = dinv[sb] * dv;
        float2 va = H2[(size_t)sa * 64 + lane];
        float2 vb = H2[(size_t)sb * 64 + lane];
        ax = fmaf(va.x, wa, ax); ay = fmaf(va.y, wa, ay);
        ax = fmaf(vb.x, wb, ax); ay = fmaf(vb.y, wb, ay);
    }
    if (e < ce) {
        int sa = sp[e];
        float wa = dinv[sa] * dv;
        float2 va = H2[(size_t)sa * 64 + lane];
        ax = fmaf(va.x, wa, ax); ay = fmaf(va.y, wa, ay);
    }
    float2 b2 = ((const float2*)bias)[lane];
    float2 o;
    o.x = fmaxf(ax + b2.x, 0.0f);
    o.y = fmaxf(ay + b2.y, 0.0f);
    ((float2*)O)[(size_t)node * 64 + lane] = o;
}

// --- pooling (batch sorted): wave-run accumulation ------------------------
__global__ void k_zero_f(float* p, int n) {
    int i = blockIdx.x * blockDim.x + threadIdx.x;
    if (i < n) p[i] = 0.0f;
}

__global__ void k_pool_seg(const float* __restrict__ H, const int* __restrict__ batch,
                           float* __restrict__ sums, float* __restrict__ cnt, int N) {
    int gw = (blockIdx.x * blockDim.x + threadIdx.x) >> 6;
    int lane = threadIdx.x & 63;
    int start = gw * 64;
    if (start >= N) return;
    int end = min(N, start + 64);
    int gcur = batch[start];
    float acc = 0.0f, c = 0.0f;
    for (int i = start; i < end; ++i) {
        int g = batch[i];
        if (g != gcur) {
            atomicAdd(&sums[(size_t)gcur * 64 + lane], acc);
            if (lane == 0) atomicAdd(&cnt[gcur], c);
            acc = 0.0f; c = 0.0f; gcur = g;
        }
        acc += H[(size_t)i * 64 + lane];
        c += 1.0f;
    }
    atomicAdd(&sums[(size_t)gcur * 64 + lane], acc);
    if (lane == 0) atomicAdd(&cnt[gcur], c);
}

// --- head: mean, fc, log_softmax ------------------------------------------
__global__ void k_head(const float* __restrict__ sums, const float* __restrict__ cnt,
                       const float* __restrict__ fcw, const float* __restrict__ fcb,
                       float* __restrict__ out, int G) {
    int g = blockIdx.x * blockDim.x + threadIdx.x;
    if (g >= G) return;
    float inv = 1.0f / fmaxf(cnt[g], 1.0f);
    float l[6];
#pragma unroll
    for (int c = 0; c < 6; ++c) {
        float acc = fcb[c];
        for (int f = 0; f < 64; ++f)
            acc = fmaf(sums[(size_t)g * 64 + f] * inv, fcw[f * 6 + c], acc);
        l[c] = acc;
    }
    float m = l[0];
#pragma unroll
    for (int c = 1; c < 6; ++c) m = fmaxf(m, l[c]);
    float se = 0.0f;
#pragma unroll
    for (int c = 0; c < 6; ++c) se += expf(l[c] - m);
    float lse = m + logf(se);
#pragma unroll
    for (int c = 0; c < 6; ++c) out[(size_t)g * 6 + c] = l[c] - lse;
}

// ---------------------------------------------------------------------------
extern "C" void kernel_launch(void* const* d_in, const int* in_sizes, int n_in,
                              void* d_out, int out_size, void* d_ws, size_t ws_size,
                              hipStream_t stream) {
    const float* x    = (const float*)d_in[0];
    const int*   eidx = (const int*)d_in[1];
    const int*   batch= (const int*)d_in[2];
    const float* W1   = (const float*)d_in[3];
    const float* b1   = (const float*)d_in[4];
    const float* W2   = (const float*)d_in[5];
    const float* b2   = (const float*)d_in[6];
    const float* W3   = (const float*)d_in[7];
    const float* b3   = (const float*)d_in[8];
    const float* fcw  = (const float*)d_in[9];
    const float* fcb  = (const float*)d_in[10];
    float* out = (float*)d_out;

    const int N = in_sizes[2];          // 100000
    const int E = in_sizes[1] / 2;      // 3200000
    const int G = out_size / 6;         // 512

    const int* src = eidx;
    const int* dst = eidx + E;

    float* ws = (float*)d_ws;
    size_t off = 0;
    auto take = [&](size_t n4) {
        float* p = ws + off;
        off += (n4 + 15) & ~(size_t)15;
        return p;
    };
    float* dinv    = take((size_t)N);
    int*   srt     = (int*)take((size_t)E);
    int*   rowoff  = (int*)take((size_t)N);
    int*   counts  = (int*)take((size_t)N);
    int*   cursor  = (int*)take((size_t)N);
    int*   partials= (int*)take(512);
    float* bufA    = take((size_t)N * 128);
    float* bufB    = take((size_t)N * 128);
    float* sums    = take((size_t)G * 64);
    float* cnt     = take((size_t)G);
    (void)ws_size;

    const int B = 256;
    const int NBLK = grid_for(N, 256);

    // --- CSR build ---
    k_zero_int<<<grid_for(N, B), B, 0, stream>>>(counts, N);
    k_count<<<grid_for(E, B), B, 0, stream>>>(dst, counts, E);
    k_scan_block<<<NBLK, 256, 0, stream>>>(counts, rowoff, partials, N);
    k_scan_partials<<<1, 512, 0, stream>>>(partials, NBLK);
    k_finalize<<<grid_for(N, B), B, 0, stream>>>(counts, rowoff, partials, cursor, dinv, N);
    k_scatter<<<grid_for(E, B), B, 0, stream>>>(src, dst, cursor, srt, E);

    // --- layer 1: x[N,128] -> h[N,64] -> agg+relu -> bufB[N,64] ---
    k_gemm_tile<128, 64, 4><<<grid_for(N, 64), B, 0, stream>>>(x, W1, bufA, N);
    k_agg_csr64<<<grid_for(N, 4), B, 0, stream>>>(srt, rowoff, counts, dinv, bufA, b1, bufB, N);

    // --- layer 2: bufB[N,64] -> h[N,128] -> agg+relu -> bufB[N,128] ---
    k_gemm_tile<64, 128, 8><<<grid_for(N, 64), B, 0, stream>>>(bufB, W2, bufA, N);
    k_agg_csr128<<<grid_for(N, 4), B, 0, stream>>>(srt, rowoff, counts, dinv, bufA, b2, bufB, N);

    // --- layer 3: bufB[N,128] -> h[N,64] -> agg+relu -> bufB[N,64] ---
    k_gemm_tile<128, 64, 4><<<grid_for(N, 64), B, 0, stream>>>(bufB, W3, bufA, N);
    k_agg_csr64<<<grid_for(N, 4), B, 0, stream>>>(srt, rowoff, counts, dinv, bufA, b3, bufB, N);

    // --- pool + head ---
    k_zero_f<<<grid_for(G * 64, B), B, 0, stream>>>(sums, G * 64);
    k_zero_f<<<grid_for(G, B), B, 0, stream>>>(cnt, G);
    k_pool_seg<<<grid_for((long long)grid_for(N, 64) * 64, B), B, 0, stream>>>(bufB, batch, sums, cnt, N);
    k_head<<<grid_for(G, 64), 64, 0, stream>>>(sums, cnt, fcw, fcb, out, G);
}